// Round 1
// baseline (3588.837 us; speedup 1.0000x reference)
//
#include <hip/hip_runtime.h>
#include <hip/hip_bf16.h>

#define NB   16384
#define TT   50
#define HH   30
#define IND  8
#define CTXD 80
#define IN2  82
#define F2   52
#define NOUT 50
#define HID  100
#define CVD  20
#define ROWS 64

__device__ __forceinline__ float sg(float x){
  x = fminf(fmaxf(x, -30.f), 30.f);
  return 1.f/(1.f+__expf(-x));
}
__device__ __forceinline__ float th(float x){
  x = fminf(fmaxf(x, -15.f), 15.f);
  float e = __expf(2.f*x);
  return (e-1.f)/(e+1.f);
}
__device__ __forceinline__ float ldv(const float* p){ return *p; }
__device__ __forceinline__ float ldv(const __hip_bfloat16* p){ return __bfloat162float(*p); }
__device__ __forceinline__ void stv(float* p, float v){ *p = v; }
__device__ __forceinline__ void stv(__hip_bfloat16* p, float v){ *p = __float2bfloat16(v); }

__device__ __forceinline__ double shfl_xor_d(double v, int m){
  long long l = __double_as_longlong(v);
  int lo = (int)(l & 0xffffffffLL), hi = (int)(l >> 32);
  lo = __shfl_xor(lo, m, 64); hi = __shfl_xor(hi, m, 64);
  return __longlong_as_double(((long long)hi << 32) | (unsigned int)(unsigned)lo);
}

// ---------------- zero BN accumulators ----------------
__global__ void k_zero(double* a, double* b){
  int i = blockIdx.x*256 + threadIdx.x;
  if (i < CTXD*2) a[i] = 0.0;
  if (i < NOUT*F2*2) b[i] = 0.0;
}

// ---------------- encoder LSTM ----------------
__global__ __launch_bounds__(256) void k_encoder(
    const float* __restrict__ x, const float* __restrict__ h0i, const float* __restrict__ c0i,
    const float* __restrict__ wih0, const float* __restrict__ whh0,
    const float* __restrict__ bih0, const float* __restrict__ bhh0,
    const float* __restrict__ wih1, const float* __restrict__ whh1,
    const float* __restrict__ bih1, const float* __restrict__ bhh1,
    float* __restrict__ h0f, float* __restrict__ h1f,
    float* __restrict__ c0f, float* __restrict__ c1f)
{
  __shared__ float h0s[2][ROWS][HH+1];
  __shared__ float h1s[2][ROWS][HH+1];
  const int r  = threadIdx.x;
  const int b  = blockIdx.x*ROWS + r;
  const int ub = __builtin_amdgcn_readfirstlane(8*(int)threadIdx.y);
  float c0[8], c1[8];
  #pragma unroll
  for (int jj=0;jj<8;++jj){
    const int j  = ub+jj;
    const int jc = j < HH ? j : HH-1;
    c0[jj] = c0i[jc];
    c1[jj] = c0i[HH+jc];
    if (j < HH){
      h0s[0][r][j] = h0i[j];
      h1s[0][r][j] = h0i[HH+j];
    }
  }
  __syncthreads();
  int cur = 0;
  for (int t=0;t<TT;++t){
    const int nxt = cur^1;
    const float4* xp = (const float4*)(x + ((size_t)b*TT + t)*IND);
    float4 xa = xp[0], xb = xp[1];
    float xv[8] = {xa.x,xa.y,xa.z,xa.w, xb.x,xb.y,xb.z,xb.w};
    float acc[8][4];
    #pragma unroll
    for (int jj=0;jj<8;++jj){
      const int jc = (ub+jj)<HH ? (ub+jj) : HH-1;
      #pragma unroll
      for (int g=0;g<4;++g){
        const int row = g*HH + jc;
        acc[jj][g] = bih0[row] + bhh0[row];
      }
    }
    #pragma unroll
    for (int k=0;k<IND;++k){
      const float v = xv[k];
      #pragma unroll
      for (int jj=0;jj<8;++jj){
        const int jc = (ub+jj)<HH ? (ub+jj) : HH-1;
        #pragma unroll
        for (int g=0;g<4;++g)
          acc[jj][g] += v * wih0[(size_t)(g*HH+jc)*IND + k];
      }
    }
    #pragma unroll 6
    for (int k=0;k<HH;++k){
      const float v = h0s[cur][r][k];
      #pragma unroll
      for (int jj=0;jj<8;++jj){
        const int jc = (ub+jj)<HH ? (ub+jj) : HH-1;
        #pragma unroll
        for (int g=0;g<4;++g)
          acc[jj][g] += v * whh0[(size_t)(g*HH+jc)*HH + k];
      }
    }
    #pragma unroll
    for (int jj=0;jj<8;++jj){
      const int j = ub+jj;
      float iv=sg(acc[jj][0]), fv=sg(acc[jj][1]), gv=th(acc[jj][2]), ov=sg(acc[jj][3]);
      float cn = fv*c0[jj] + iv*gv;
      c0[jj] = cn;
      if (j<HH) h0s[nxt][r][j] = ov*th(cn);
    }
    __syncthreads();
    // layer 1
    #pragma unroll
    for (int jj=0;jj<8;++jj){
      const int jc = (ub+jj)<HH ? (ub+jj) : HH-1;
      #pragma unroll
      for (int g=0;g<4;++g){
        const int row = g*HH + jc;
        acc[jj][g] = bih1[row] + bhh1[row];
      }
    }
    #pragma unroll 6
    for (int k=0;k<HH;++k){
      const float v = h0s[nxt][r][k];
      #pragma unroll
      for (int jj=0;jj<8;++jj){
        const int jc = (ub+jj)<HH ? (ub+jj) : HH-1;
        #pragma unroll
        for (int g=0;g<4;++g)
          acc[jj][g] += v * wih1[(size_t)(g*HH+jc)*HH + k];
      }
    }
    #pragma unroll 6
    for (int k=0;k<HH;++k){
      const float v = h1s[cur][r][k];
      #pragma unroll
      for (int jj=0;jj<8;++jj){
        const int jc = (ub+jj)<HH ? (ub+jj) : HH-1;
        #pragma unroll
        for (int g=0;g<4;++g)
          acc[jj][g] += v * whh1[(size_t)(g*HH+jc)*HH + k];
      }
    }
    #pragma unroll
    for (int jj=0;jj<8;++jj){
      const int j = ub+jj;
      float iv=sg(acc[jj][0]), fv=sg(acc[jj][1]), gv=th(acc[jj][2]), ov=sg(acc[jj][3]);
      float cn = fv*c1[jj] + iv*gv;
      c1[jj] = cn;
      if (j<HH) h1s[nxt][r][j] = ov*th(cn);
    }
    __syncthreads();
    cur = nxt;
  }
  #pragma unroll
  for (int jj=0;jj<8;++jj){
    const int j = ub+jj;
    if (j<HH){
      h0f[(size_t)b*HH+j] = h0s[cur][r][j];
      h1f[(size_t)b*HH+j] = h1s[cur][r][j];
      c0f[(size_t)b*HH+j] = c0[jj];
      c1f[(size_t)b*HH+j] = c1[jj];
    }
  }
}

// ---------------- conv path, one row per 64-thread block ----------------
__global__ __launch_bounds__(64) void k_conv(
    const float* __restrict__ x,
    const float* __restrict__ w1, const float* __restrict__ b1,
    const float* __restrict__ w2, const float* __restrict__ b2,
    const float* __restrict__ w3, const float* __restrict__ b3,
    const float* __restrict__ fw, const float* __restrict__ fb,
    float* __restrict__ xcg)
{
  __shared__ float xr[IND][TT];
  __shared__ float p1[32][23];
  __shared__ float p2[64][11];
  __shared__ float p3[512];
  __shared__ float red[64][21];
  const int b = blockIdx.x, tid = threadIdx.x;
  for (int i=tid;i<TT*IND;i+=64){
    float v = x[(size_t)b*(TT*IND) + i];
    xr[i % IND][i / IND] = v;
  }
  __syncthreads();
  if (tid < 23){
    float a0[32], a1[32];
    #pragma unroll
    for (int oc=0;oc<32;++oc){ float bb=b1[oc]; a0[oc]=bb; a1[oc]=bb; }
    for (int ic=0;ic<IND;++ic){
      float xw[6];
      #pragma unroll
      for (int q=0;q<6;++q) xw[q] = xr[ic][2*tid+q];
      #pragma unroll
      for (int kk=0;kk<5;++kk){
        float va = xw[kk], vb = xw[kk+1];
        #pragma unroll
        for (int oc=0;oc<32;++oc){
          float w = w1[(size_t)(oc*IND+ic)*5 + kk];
          a0[oc] += w*va; a1[oc] += w*vb;
        }
      }
    }
    #pragma unroll
    for (int oc=0;oc<32;++oc)
      p1[oc][tid] = fmaxf(fmaxf(a0[oc],0.f), fmaxf(a1[oc],0.f));
  }
  __syncthreads();
  { // conv2: lane = oc
    float acc[21];
    #pragma unroll
    for (int t=0;t<21;++t) acc[t] = b2[tid];
    for (int ic=0;ic<32;++ic){
      float xv[23];
      #pragma unroll
      for (int q=0;q<23;++q) xv[q] = p1[ic][q];
      #pragma unroll
      for (int kk=0;kk<3;++kk){
        float w = w2[(size_t)(tid*32+ic)*3 + kk];
        #pragma unroll
        for (int t=0;t<21;++t) acc[t] += w*xv[t+kk];
      }
    }
    #pragma unroll
    for (int p=0;p<10;++p)
      p2[tid][p] = fmaxf(fmaxf(acc[2*p],0.f), fmaxf(acc[2*p+1],0.f));
  }
  __syncthreads();
  { // conv3: oc = tid and tid+64
    float a0[8], a1[8];
    #pragma unroll
    for (int t=0;t<8;++t){ a0[t]=b3[tid]; a1[t]=b3[tid+64]; }
    for (int ic=0;ic<64;++ic){
      float xv[10];
      #pragma unroll
      for (int q=0;q<10;++q) xv[q] = p2[ic][q];
      #pragma unroll
      for (int kk=0;kk<3;++kk){
        float wa = w3[(size_t)(tid*64+ic)*3 + kk];
        float wb = w3[(size_t)((tid+64)*64+ic)*3 + kk];
        #pragma unroll
        for (int t=0;t<8;++t){ a0[t]+=wa*xv[t+kk]; a1[t]+=wb*xv[t+kk]; }
      }
    }
    #pragma unroll
    for (int p=0;p<4;++p){
      p3[tid*4+p]      = fmaxf(fmaxf(a0[2*p],0.f), fmaxf(a0[2*p+1],0.f));
      p3[(tid+64)*4+p] = fmaxf(fmaxf(a1[2*p],0.f), fmaxf(a1[2*p+1],0.f));
    }
  }
  __syncthreads();
  { // fc: k-slice per lane
    float xs[8];
    #pragma unroll
    for (int q=0;q<8;++q) xs[q] = p3[tid*8+q];
    float acc[20];
    #pragma unroll
    for (int j=0;j<20;++j){
      float a = 0.f;
      #pragma unroll
      for (int q=0;q<8;++q) a += xs[q] * fw[(size_t)j*512 + tid*8 + q];
      acc[j] = a;
    }
    #pragma unroll
    for (int j=0;j<20;++j) red[tid][j] = acc[j];
  }
  __syncthreads();
  if (tid < 20){
    float s = fb[tid];
    for (int l=0;l<64;++l) s += red[l][tid];
    xcg[(size_t)b*CVD + tid] = fmaxf(s, 0.f);
  }
}

// ---------------- BN1 stats ----------------
__global__ __launch_bounds__(128) void k_bn1s(const float* __restrict__ h0f, const float* __restrict__ h1f,
    const float* __restrict__ xcg, double* __restrict__ s1)
{
  int f = threadIdx.x;
  if (f >= CTXD) return;
  int r0 = blockIdx.x*128;
  double s=0.0, q=0.0;
  for (int i=0;i<128;++i){
    int r = r0+i;
    float v = (f<HH) ? h0f[(size_t)r*HH+f] : (f<2*HH) ? h1f[(size_t)r*HH + f-HH] : xcg[(size_t)r*CVD + f-2*HH];
    s += (double)v; q += (double)v*(double)v;
  }
  atomicAdd(&s1[f*2],   s);
  atomicAdd(&s1[f*2+1], q);
}

__global__ void k_fin1(const double* __restrict__ s1, float* __restrict__ st1){
  int f = threadIdx.x;
  if (f >= CTXD) return;
  double m = s1[f*2]/(double)NB;
  double var = s1[f*2+1]/(double)NB - m*m;
  if (var < 0.0) var = 0.0;
  st1[f*2]   = (float)m;
  st1[f*2+1] = (float)(1.0/sqrt(var + 1e-5));
}

__global__ __launch_bounds__(256) void k_context(const float* __restrict__ h0f, const float* __restrict__ h1f,
    const float* __restrict__ xcg, const float* __restrict__ st1,
    const float* __restrict__ g1, const float* __restrict__ bb1, float* __restrict__ ctx)
{
  int idx = blockIdx.x*256 + threadIdx.x;
  if (idx >= NB*CTXD) return;
  int rr = idx / CTXD, f = idx - rr*CTXD;
  float v = (f<HH) ? h0f[(size_t)rr*HH+f] : (f<2*HH) ? h1f[(size_t)rr*HH + f-HH] : xcg[(size_t)rr*CVD + f-2*HH];
  ctx[idx] = (v - st1[f*2]) * st1[f*2+1] * g1[f] + bb1[f];
}

// ---------------- decoder pass 1: LSTM chain + stats + h1n store ----------------
template<typename ST>
__global__ __launch_bounds__(256) void k_dec1(
    const float* __restrict__ x, const float* __restrict__ y,
    const float* __restrict__ ctx, const float* __restrict__ xcg,
    const float* __restrict__ wih0, const float* __restrict__ whh0,
    const float* __restrict__ bih0, const float* __restrict__ bhh0,
    const float* __restrict__ wih1, const float* __restrict__ whh1,
    const float* __restrict__ bih1, const float* __restrict__ bhh1,
    const float* __restrict__ h0fi, const float* __restrict__ h1fi,
    const float* __restrict__ c0fi, const float* __restrict__ c1fi,
    ST* __restrict__ h1n, double* __restrict__ s2)
{
  __shared__ float ctxs[ROWS][CTXD+1];
  __shared__ float xcs[ROWS][CVD+1];
  __shared__ float h0s[2][ROWS][HH+1];
  __shared__ float h1s[2][ROWS][HH+1];
  const int r = threadIdx.x;
  const int b = blockIdx.x*ROWS + r;
  const int tid = threadIdx.y*ROWS + r;
  for (int i=tid; i<ROWS*CTXD; i+=256){
    int rr = i/CTXD, ff = i - rr*CTXD;
    ctxs[rr][ff] = ctx[((size_t)blockIdx.x*ROWS + rr)*CTXD + ff];
  }
  for (int i=tid; i<ROWS*CVD; i+=256){
    int rr = i/CVD, ff = i - rr*CVD;
    xcs[rr][ff] = xcg[((size_t)blockIdx.x*ROWS + rr)*CVD + ff];
  }
  const int ub = __builtin_amdgcn_readfirstlane(8*(int)threadIdx.y);
  const int wy = ub >> 3;
  float c0[8], c1[8];
  #pragma unroll
  for (int jj=0;jj<8;++jj){
    const int j = ub+jj;
    const int jc = j<HH ? j : HH-1;
    c0[jj] = c0fi[(size_t)b*HH + jc];
    c1[jj] = c1fi[(size_t)b*HH + jc];
    if (j<HH){
      h0s[0][r][j] = h0fi[(size_t)b*HH + j];
      h1s[0][r][j] = h1fi[(size_t)b*HH + j];
    }
  }
  float tcur = x[(size_t)b*(TT*IND) + (TT-1)*IND + 7];
  float yi   = x[(size_t)b*(TT*IND) + (TT-1)*IND + 0];
  __syncthreads();
  int cur = 0;
  for (int s=0; s<NOUT; ++s){
    const int nxt = cur^1;
    tcur = fmodf(tcur + 15.f, 1440.f);
    float acc[8][4];
    #pragma unroll
    for (int jj=0;jj<8;++jj){
      const int jc = (ub+jj)<HH ? (ub+jj) : HH-1;
      #pragma unroll
      for (int g=0;g<4;++g){
        const int row = g*HH+jc;
        acc[jj][g] = bih0[row] + bhh0[row]
                   + tcur * wih0[(size_t)row*IN2 + 80]
                   + yi   * wih0[(size_t)row*IN2 + 81];
      }
    }
    #pragma unroll 4
    for (int k=0;k<CTXD;++k){
      const float v = ctxs[r][k];
      #pragma unroll
      for (int jj=0;jj<8;++jj){
        const int jc = (ub+jj)<HH ? (ub+jj) : HH-1;
        #pragma unroll
        for (int g=0;g<4;++g)
          acc[jj][g] += v * wih0[(size_t)(g*HH+jc)*IN2 + k];
      }
    }
    #pragma unroll 6
    for (int k=0;k<HH;++k){
      const float v = h0s[cur][r][k];
      #pragma unroll
      for (int jj=0;jj<8;++jj){
        const int jc = (ub+jj)<HH ? (ub+jj) : HH-1;
        #pragma unroll
        for (int g=0;g<4;++g)
          acc[jj][g] += v * whh0[(size_t)(g*HH+jc)*HH + k];
      }
    }
    #pragma unroll
    for (int jj=0;jj<8;++jj){
      const int j = ub+jj;
      float iv=sg(acc[jj][0]), fv=sg(acc[jj][1]), gv=th(acc[jj][2]), ov=sg(acc[jj][3]);
      float cn = fv*c0[jj] + iv*gv;
      c0[jj] = cn;
      if (j<HH) h0s[nxt][r][j] = ov*th(cn);
    }
    __syncthreads();
    #pragma unroll
    for (int jj=0;jj<8;++jj){
      const int jc = (ub+jj)<HH ? (ub+jj) : HH-1;
      #pragma unroll
      for (int g=0;g<4;++g){
        const int row = g*HH+jc;
        acc[jj][g] = bih1[row] + bhh1[row];
      }
    }
    #pragma unroll 6
    for (int k=0;k<HH;++k){
      const float v = h0s[nxt][r][k];
      #pragma unroll
      for (int jj=0;jj<8;++jj){
        const int jc = (ub+jj)<HH ? (ub+jj) : HH-1;
        #pragma unroll
        for (int g=0;g<4;++g)
          acc[jj][g] += v * wih1[(size_t)(g*HH+jc)*HH + k];
      }
    }
    #pragma unroll 6
    for (int k=0;k<HH;++k){
      const float v = h1s[cur][r][k];
      #pragma unroll
      for (int jj=0;jj<8;++jj){
        const int jc = (ub+jj)<HH ? (ub+jj) : HH-1;
        #pragma unroll
        for (int g=0;g<4;++g)
          acc[jj][g] += v * whh1[(size_t)(g*HH+jc)*HH + k];
      }
    }
    #pragma unroll
    for (int jj=0;jj<8;++jj){
      const int j = ub+jj;
      float iv=sg(acc[jj][0]), fv=sg(acc[jj][1]), gv=th(acc[jj][2]), ov=sg(acc[jj][3]);
      float cn = fv*c1[jj] + iv*gv;
      c1[jj] = cn;
      if (j<HH) h1s[nxt][r][j] = ov*th(cn);
    }
    __syncthreads();
    // per-step feature stats (52 features, 13 per wave), reduced over the 64 rows in this wave
    #pragma unroll 1
    for (int q=0;q<13;++q){
      const int f = wy*13 + q;
      float v;
      if (f < HH) v = h1s[nxt][r][f];
      else if (f < HH+CVD) v = xcs[r][f-HH];
      else if (f == HH+CVD) v = tcur;
      else v = yi;
      double sv = (double)v, sq = (double)v*(double)v;
      #pragma unroll
      for (int m=32;m>0;m>>=1){ sv += shfl_xor_d(sv,m); sq += shfl_xor_d(sq,m); }
      if (r==0){
        atomicAdd(&s2[((size_t)s*F2+f)*2+0], sv);
        atomicAdd(&s2[((size_t)s*F2+f)*2+1], sq);
      }
    }
    #pragma unroll
    for (int jj=0;jj<8;++jj){
      const int j = ub+jj;
      if (j<HH) stv(&h1n[((size_t)s*HH+j)*NB + b], h1s[nxt][r][j]);
    }
    yi = y[(size_t)b*NOUT + s];   // teacher forcing for next step
    cur = nxt;
  }
}

__global__ __launch_bounds__(256) void k_fin2(const double* __restrict__ s2, float* __restrict__ m2, float* __restrict__ r2){
  int i = blockIdx.x*256 + threadIdx.x;
  if (i >= NOUT*F2) return;
  double m = s2[i*2]/(double)NB;
  double var = s2[i*2+1]/(double)NB - m*m;
  if (var < 0.0) var = 0.0;
  m2[i] = (float)m;
  r2[i] = (float)(1.0/sqrt(var + 1e-5));
}

// ---------------- decoder pass 2: BN2 + dense readout ----------------
template<typename ST>
__global__ __launch_bounds__(256) void k_readout(
    const float* __restrict__ x, const float* __restrict__ y, const ST* __restrict__ h1n,
    const float* __restrict__ xcg, const float* __restrict__ m2, const float* __restrict__ r2,
    const float* __restrict__ g2, const float* __restrict__ b2,
    const float* __restrict__ Wd, const float* __restrict__ Bd,
    const float* __restrict__ Ud, const float* __restrict__ Cd, float* __restrict__ out)
{
  const int s  = blockIdx.y;
  const int rr = blockIdx.x*256 + threadIdx.x;
  float feat[F2];
  #pragma unroll
  for (int f=0; f<HH; ++f) feat[f] = ldv(&h1n[((size_t)s*HH+f)*NB + rr]);
  #pragma unroll
  for (int f=0; f<CVD; ++f) feat[HH+f] = xcg[(size_t)rr*CVD + f];
  float t0 = x[(size_t)rr*(TT*IND) + (TT-1)*IND + 7];
  for (int i=0;i<=s;++i) t0 = fmodf(t0 + 15.f, 1440.f);
  feat[HH+CVD] = t0;
  feat[HH+CVD+1] = (s==0) ? x[(size_t)rr*(TT*IND) + (TT-1)*IND + 0] : y[(size_t)rr*NOUT + (s-1)];
  #pragma unroll
  for (int f=0; f<F2; ++f)
    feat[f] = (feat[f] - m2[s*F2+f]) * r2[s*F2+f] * g2[f] + b2[f];
  float yv = Cd[s];
  #pragma unroll 1
  for (int jb=0; jb<HID; jb+=10){
    float a[10];
    #pragma unroll
    for (int jt=0;jt<10;++jt) a[jt] = Bd[(size_t)s*HID + jb + jt];
    #pragma unroll 4
    for (int k=0;k<F2;++k){
      const float v = feat[k];
      #pragma unroll
      for (int jt=0;jt<10;++jt)
        a[jt] += v * Wd[((size_t)s*F2 + k)*HID + jb + jt];
    }
    #pragma unroll
    for (int jt=0;jt<10;++jt)
      yv += fmaxf(a[jt], 0.f) * Ud[(size_t)s*HID + jb + jt];
  }
  out[(size_t)rr*NOUT + s] = yv;
}

// ---------------- host ----------------
extern "C" void kernel_launch(void* const* d_in, const int* in_sizes, int n_in,
                              void* d_out, int out_size, void* d_ws, size_t ws_size,
                              hipStream_t stream)
{
  const float* x    = (const float*)d_in[0];
  const float* y    = (const float*)d_in[1];
  const float* h0i  = (const float*)d_in[2];
  const float* c0i  = (const float*)d_in[3];
  const float* wih0 = (const float*)d_in[4];
  const float* whh0 = (const float*)d_in[5];
  const float* bih0 = (const float*)d_in[6];
  const float* bhh0 = (const float*)d_in[7];
  const float* wih1 = (const float*)d_in[8];
  const float* whh1 = (const float*)d_in[9];
  const float* bih1 = (const float*)d_in[10];
  const float* bhh1 = (const float*)d_in[11];
  const float* w2ih0= (const float*)d_in[12];
  const float* w2hh0= (const float*)d_in[13];
  const float* b2ih0= (const float*)d_in[14];
  const float* b2hh0= (const float*)d_in[15];
  const float* w2ih1= (const float*)d_in[16];
  const float* w2hh1= (const float*)d_in[17];
  const float* b2ih1= (const float*)d_in[18];
  const float* b2hh1= (const float*)d_in[19];
  const float* c1w  = (const float*)d_in[20];
  const float* c1b  = (const float*)d_in[21];
  const float* c2w  = (const float*)d_in[22];
  const float* c2b  = (const float*)d_in[23];
  const float* c3w  = (const float*)d_in[24];
  const float* c3b  = (const float*)d_in[25];
  const float* fcw  = (const float*)d_in[26];
  const float* fcb  = (const float*)d_in[27];
  const float* bn1g = (const float*)d_in[28];
  const float* bn1b = (const float*)d_in[29];
  const float* bn2g = (const float*)d_in[30];
  const float* bn2b = (const float*)d_in[31];
  const float* Wd   = (const float*)d_in[32];
  const float* Bd   = (const float*)d_in[33];
  const float* Ud   = (const float*)d_in[34];
  const float* Cd   = (const float*)d_in[35];
  float* out = (float*)d_out;

  char* base = (char*)d_ws;
  size_t off = 0;
  auto take = [&](size_t bytes)->char*{
    char* p = base + off;
    off = (off + bytes + 255) & ~(size_t)255;
    return p;
  };
  float*  h0f = (float*) take((size_t)NB*HH*sizeof(float));
  float*  h1f = (float*) take((size_t)NB*HH*sizeof(float));
  float*  c0f = (float*) take((size_t)NB*HH*sizeof(float));
  float*  c1f = (float*) take((size_t)NB*HH*sizeof(float));
  float*  xcg = (float*) take((size_t)NB*CVD*sizeof(float));
  float*  ctx = (float*) take((size_t)NB*CTXD*sizeof(float));
  double* s1  = (double*)take((size_t)CTXD*2*sizeof(double));
  float*  st1 = (float*) take((size_t)CTXD*2*sizeof(float));
  double* s2  = (double*)take((size_t)NOUT*F2*2*sizeof(double));
  float*  m2  = (float*) take((size_t)NOUT*F2*sizeof(float));
  float*  r2  = (float*) take((size_t)NOUT*F2*sizeof(float));
  size_t fixed = off;
  size_t rem = (ws_size > fixed) ? (ws_size - fixed) : 0;
  bool f32st = rem >= (size_t)NOUT*HH*NB*sizeof(float);
  void* h1n = (void*)(base + off);

  k_zero<<<dim3((NOUT*F2*2 + 255)/256), dim3(256), 0, stream>>>(s1, s2);
  k_encoder<<<dim3(NB/ROWS), dim3(ROWS,4), 0, stream>>>(x, h0i, c0i,
      wih0, whh0, bih0, bhh0, wih1, whh1, bih1, bhh1, h0f, h1f, c0f, c1f);
  k_conv<<<dim3(NB), dim3(64), 0, stream>>>(x, c1w, c1b, c2w, c2b, c3w, c3b, fcw, fcb, xcg);
  k_bn1s<<<dim3(NB/128), dim3(128), 0, stream>>>(h0f, h1f, xcg, s1);
  k_fin1<<<dim3(1), dim3(128), 0, stream>>>(s1, st1);
  k_context<<<dim3((NB*CTXD + 255)/256), dim3(256), 0, stream>>>(h0f, h1f, xcg, st1, bn1g, bn1b, ctx);
  if (f32st){
    k_dec1<float><<<dim3(NB/ROWS), dim3(ROWS,4), 0, stream>>>(x, y, ctx, xcg,
        w2ih0, w2hh0, b2ih0, b2hh0, w2ih1, w2hh1, b2ih1, b2hh1,
        h0f, h1f, c0f, c1f, (float*)h1n, s2);
    k_fin2<<<dim3((NOUT*F2 + 255)/256), dim3(256), 0, stream>>>(s2, m2, r2);
    k_readout<float><<<dim3(NB/256, NOUT), dim3(256), 0, stream>>>(x, y, (const float*)h1n,
        xcg, m2, r2, bn2g, bn2b, Wd, Bd, Ud, Cd, out);
  } else {
    k_dec1<__hip_bfloat16><<<dim3(NB/ROWS), dim3(ROWS,4), 0, stream>>>(x, y, ctx, xcg,
        w2ih0, w2hh0, b2ih0, b2hh0, w2ih1, w2hh1, b2ih1, b2hh1,
        h0f, h1f, c0f, c1f, (__hip_bfloat16*)h1n, s2);
    k_fin2<<<dim3((NOUT*F2 + 255)/256), dim3(256), 0, stream>>>(s2, m2, r2);
    k_readout<__hip_bfloat16><<<dim3(NB/256, NOUT), dim3(256), 0, stream>>>(x, y, (const __hip_bfloat16*)h1n,
        xcg, m2, r2, bn2g, bn2b, Wd, Bd, Ud, Cd, out);
  }
}

// Round 2
// 3148.665 us; speedup vs baseline: 1.1398x; 1.1398x over previous
//
#include <hip/hip_runtime.h>
#include <hip/hip_bf16.h>

#define NB   16384
#define TT   50
#define HH   30
#define IND  8
#define CTXD 80
#define IN2  82
#define F2   52
#define NOUT 50
#define HID  100
#define CVD  20
#define ROWS 64
#define GRP  16   // y-groups (waves) per block; each thread owns 2 hidden units

__device__ __forceinline__ float sg(float x){
  x = fminf(fmaxf(x, -30.f), 30.f);
  return 1.f/(1.f+__expf(-x));
}
__device__ __forceinline__ float th(float x){
  x = fminf(fmaxf(x, -15.f), 15.f);
  float e = __expf(2.f*x);
  return (e-1.f)/(e+1.f);
}
__device__ __forceinline__ float ldv(const float* p){ return *p; }
__device__ __forceinline__ float ldv(const __hip_bfloat16* p){ return __bfloat162float(*p); }
__device__ __forceinline__ void stv(float* p, float v){ *p = v; }
__device__ __forceinline__ void stv(__hip_bfloat16* p, float v){ *p = __float2bfloat16(v); }

__device__ __forceinline__ double shfl_xor_d(double v, int m){
  long long l = __double_as_longlong(v);
  int lo = (int)(l & 0xffffffffLL), hi = (int)(l >> 32);
  lo = __shfl_xor(lo, m, 64); hi = __shfl_xor(hi, m, 64);
  return __longlong_as_double(((long long)hi << 32) | (unsigned int)(unsigned)lo);
}

// ---------------- zero BN accumulators ----------------
__global__ void k_zero(double* a, double* b){
  int i = blockIdx.x*256 + threadIdx.x;
  if (i < CTXD*2) a[i] = 0.0;
  if (i < NOUT*F2*2) b[i] = 0.0;
}

// ---------------- encoder LSTM ----------------
__global__ __launch_bounds__(ROWS*GRP) void k_encoder(
    const float* __restrict__ x, const float* __restrict__ h0i, const float* __restrict__ c0i,
    const float* __restrict__ wih0, const float* __restrict__ whh0,
    const float* __restrict__ bih0, const float* __restrict__ bhh0,
    const float* __restrict__ wih1, const float* __restrict__ whh1,
    const float* __restrict__ bih1, const float* __restrict__ bhh1,
    float* __restrict__ h0f, float* __restrict__ h1f,
    float* __restrict__ c0f, float* __restrict__ c1f)
{
  __shared__ float h0s[2][ROWS][HH+1];
  __shared__ float h1s[2][ROWS][HH+1];
  const int r  = threadIdx.x;
  const int b  = blockIdx.x*ROWS + r;
  const int ub = __builtin_amdgcn_readfirstlane(2*(int)threadIdx.y);
  float c0[2], c1[2];
  float bs0[2][4], bs1[2][4];   // hoisted bias sums
  #pragma unroll
  for (int jj=0;jj<2;++jj){
    const int j  = ub+jj;
    const int jc = j < HH ? j : HH-1;
    c0[jj] = c0i[jc];
    c1[jj] = c0i[HH+jc];
    #pragma unroll
    for (int g=0;g<4;++g){
      bs0[jj][g] = bih0[g*HH+jc] + bhh0[g*HH+jc];
      bs1[jj][g] = bih1[g*HH+jc] + bhh1[g*HH+jc];
    }
    if (j < HH && threadIdx.y < GRP){
      h0s[0][r][j] = h0i[j];
      h1s[0][r][j] = h0i[HH+j];
    }
  }
  __syncthreads();
  int cur = 0;
  for (int t=0;t<TT;++t){
    const int nxt = cur^1;
    const float4* xp = (const float4*)(x + ((size_t)b*TT + t)*IND);
    float4 xa = xp[0], xb = xp[1];
    float xv[8] = {xa.x,xa.y,xa.z,xa.w, xb.x,xb.y,xb.z,xb.w};
    float acc[2][4];
    #pragma unroll
    for (int jj=0;jj<2;++jj)
      #pragma unroll
      for (int g=0;g<4;++g) acc[jj][g] = bs0[jj][g];
    #pragma unroll
    for (int k=0;k<IND;++k){
      const float v = xv[k];
      #pragma unroll
      for (int jj=0;jj<2;++jj){
        const int jc = (ub+jj)<HH ? (ub+jj) : HH-1;
        #pragma unroll
        for (int g=0;g<4;++g)
          acc[jj][g] += v * wih0[(size_t)(g*HH+jc)*IND + k];
      }
    }
    #pragma unroll 10
    for (int k=0;k<HH;++k){
      const float v = h0s[cur][r][k];
      #pragma unroll
      for (int jj=0;jj<2;++jj){
        const int jc = (ub+jj)<HH ? (ub+jj) : HH-1;
        #pragma unroll
        for (int g=0;g<4;++g)
          acc[jj][g] += v * whh0[(size_t)(g*HH+jc)*HH + k];
      }
    }
    #pragma unroll
    for (int jj=0;jj<2;++jj){
      const int j = ub+jj;
      float iv=sg(acc[jj][0]), fv=sg(acc[jj][1]), gv=th(acc[jj][2]), ov=sg(acc[jj][3]);
      float cn = fv*c0[jj] + iv*gv;
      c0[jj] = cn;
      if (j<HH) h0s[nxt][r][j] = ov*th(cn);
    }
    __syncthreads();
    // layer 1
    #pragma unroll
    for (int jj=0;jj<2;++jj)
      #pragma unroll
      for (int g=0;g<4;++g) acc[jj][g] = bs1[jj][g];
    #pragma unroll 10
    for (int k=0;k<HH;++k){
      const float v = h0s[nxt][r][k];
      #pragma unroll
      for (int jj=0;jj<2;++jj){
        const int jc = (ub+jj)<HH ? (ub+jj) : HH-1;
        #pragma unroll
        for (int g=0;g<4;++g)
          acc[jj][g] += v * wih1[(size_t)(g*HH+jc)*HH + k];
      }
    }
    #pragma unroll 10
    for (int k=0;k<HH;++k){
      const float v = h1s[cur][r][k];
      #pragma unroll
      for (int jj=0;jj<2;++jj){
        const int jc = (ub+jj)<HH ? (ub+jj) : HH-1;
        #pragma unroll
        for (int g=0;g<4;++g)
          acc[jj][g] += v * whh1[(size_t)(g*HH+jc)*HH + k];
      }
    }
    #pragma unroll
    for (int jj=0;jj<2;++jj){
      const int j = ub+jj;
      float iv=sg(acc[jj][0]), fv=sg(acc[jj][1]), gv=th(acc[jj][2]), ov=sg(acc[jj][3]);
      float cn = fv*c1[jj] + iv*gv;
      c1[jj] = cn;
      if (j<HH) h1s[nxt][r][j] = ov*th(cn);
    }
    __syncthreads();
    cur = nxt;
  }
  #pragma unroll
  for (int jj=0;jj<2;++jj){
    const int j = ub+jj;
    if (j<HH){
      h0f[(size_t)b*HH+j] = h0s[cur][r][j];
      h1f[(size_t)b*HH+j] = h1s[cur][r][j];
      c0f[(size_t)b*HH+j] = c0[jj];
      c1f[(size_t)b*HH+j] = c1[jj];
    }
  }
}

// ---------------- conv path, one row per 64-thread block ----------------
__global__ __launch_bounds__(64) void k_conv(
    const float* __restrict__ x,
    const float* __restrict__ w1, const float* __restrict__ b1,
    const float* __restrict__ w2, const float* __restrict__ b2,
    const float* __restrict__ w3, const float* __restrict__ b3,
    const float* __restrict__ fw, const float* __restrict__ fb,
    float* __restrict__ xcg)
{
  __shared__ float xr[IND][TT];
  __shared__ float p1[32][23];
  __shared__ float p2[64][11];
  __shared__ float p3[512];
  __shared__ float red[64][21];
  const int b = blockIdx.x, tid = threadIdx.x;
  for (int i=tid;i<TT*IND;i+=64){
    float v = x[(size_t)b*(TT*IND) + i];
    xr[i % IND][i / IND] = v;
  }
  __syncthreads();
  if (tid < 23){
    float a0[32], a1[32];
    #pragma unroll
    for (int oc=0;oc<32;++oc){ float bb=b1[oc]; a0[oc]=bb; a1[oc]=bb; }
    for (int ic=0;ic<IND;++ic){
      float xw[6];
      #pragma unroll
      for (int q=0;q<6;++q) xw[q] = xr[ic][2*tid+q];
      #pragma unroll
      for (int kk=0;kk<5;++kk){
        float va = xw[kk], vb = xw[kk+1];
        #pragma unroll
        for (int oc=0;oc<32;++oc){
          float w = w1[(size_t)(oc*IND+ic)*5 + kk];
          a0[oc] += w*va; a1[oc] += w*vb;
        }
      }
    }
    #pragma unroll
    for (int oc=0;oc<32;++oc)
      p1[oc][tid] = fmaxf(fmaxf(a0[oc],0.f), fmaxf(a1[oc],0.f));
  }
  __syncthreads();
  { // conv2: lane = oc
    float acc[21];
    #pragma unroll
    for (int t=0;t<21;++t) acc[t] = b2[tid];
    for (int ic=0;ic<32;++ic){
      float xv[23];
      #pragma unroll
      for (int q=0;q<23;++q) xv[q] = p1[ic][q];
      #pragma unroll
      for (int kk=0;kk<3;++kk){
        float w = w2[(size_t)(tid*32+ic)*3 + kk];
        #pragma unroll
        for (int t=0;t<21;++t) acc[t] += w*xv[t+kk];
      }
    }
    #pragma unroll
    for (int p=0;p<10;++p)
      p2[tid][p] = fmaxf(fmaxf(acc[2*p],0.f), fmaxf(acc[2*p+1],0.f));
  }
  __syncthreads();
  { // conv3: oc = tid and tid+64
    float a0[8], a1[8];
    #pragma unroll
    for (int t=0;t<8;++t){ a0[t]=b3[tid]; a1[t]=b3[tid+64]; }
    for (int ic=0;ic<64;++ic){
      float xv[10];
      #pragma unroll
      for (int q=0;q<10;++q) xv[q] = p2[ic][q];
      #pragma unroll
      for (int kk=0;kk<3;++kk){
        float wa = w3[(size_t)(tid*64+ic)*3 + kk];
        float wb = w3[(size_t)((tid+64)*64+ic)*3 + kk];
        #pragma unroll
        for (int t=0;t<8;++t){ a0[t]+=wa*xv[t+kk]; a1[t]+=wb*xv[t+kk]; }
      }
    }
    #pragma unroll
    for (int p=0;p<4;++p){
      p3[tid*4+p]      = fmaxf(fmaxf(a0[2*p],0.f), fmaxf(a0[2*p+1],0.f));
      p3[(tid+64)*4+p] = fmaxf(fmaxf(a1[2*p],0.f), fmaxf(a1[2*p+1],0.f));
    }
  }
  __syncthreads();
  { // fc: k-slice per lane
    float xs[8];
    #pragma unroll
    for (int q=0;q<8;++q) xs[q] = p3[tid*8+q];
    float acc[20];
    #pragma unroll
    for (int j=0;j<20;++j){
      float a = 0.f;
      #pragma unroll
      for (int q=0;q<8;++q) a += xs[q] * fw[(size_t)j*512 + tid*8 + q];
      acc[j] = a;
    }
    #pragma unroll
    for (int j=0;j<20;++j) red[tid][j] = acc[j];
  }
  __syncthreads();
  if (tid < 20){
    float s = fb[tid];
    for (int l=0;l<64;++l) s += red[l][tid];
    xcg[(size_t)b*CVD + tid] = fmaxf(s, 0.f);
  }
}

// ---------------- BN1 stats ----------------
__global__ __launch_bounds__(128) void k_bn1s(const float* __restrict__ h0f, const float* __restrict__ h1f,
    const float* __restrict__ xcg, double* __restrict__ s1)
{
  int f = threadIdx.x;
  if (f >= CTXD) return;
  int r0 = blockIdx.x*128;
  double s=0.0, q=0.0;
  for (int i=0;i<128;++i){
    int r = r0+i;
    float v = (f<HH) ? h0f[(size_t)r*HH+f] : (f<2*HH) ? h1f[(size_t)r*HH + f-HH] : xcg[(size_t)r*CVD + f-2*HH];
    s += (double)v; q += (double)v*(double)v;
  }
  atomicAdd(&s1[f*2],   s);
  atomicAdd(&s1[f*2+1], q);
}

__global__ void k_fin1(const double* __restrict__ s1, float* __restrict__ st1){
  int f = threadIdx.x;
  if (f >= CTXD) return;
  double m = s1[f*2]/(double)NB;
  double var = s1[f*2+1]/(double)NB - m*m;
  if (var < 0.0) var = 0.0;
  st1[f*2]   = (float)m;
  st1[f*2+1] = (float)(1.0/sqrt(var + 1e-5));
}

__global__ __launch_bounds__(256) void k_context(const float* __restrict__ h0f, const float* __restrict__ h1f,
    const float* __restrict__ xcg, const float* __restrict__ st1,
    const float* __restrict__ g1, const float* __restrict__ bb1, float* __restrict__ ctx)
{
  int idx = blockIdx.x*256 + threadIdx.x;
  if (idx >= NB*CTXD) return;
  int rr = idx / CTXD, f = idx - rr*CTXD;
  float v = (f<HH) ? h0f[(size_t)rr*HH+f] : (f<2*HH) ? h1f[(size_t)rr*HH + f-HH] : xcg[(size_t)rr*CVD + f-2*HH];
  ctx[idx] = (v - st1[f*2]) * st1[f*2+1] * g1[f] + bb1[f];
}

// ---------------- decoder pass 1: LSTM chain + stats + h1n store ----------------
template<typename ST>
__global__ __launch_bounds__(ROWS*GRP) void k_dec1(
    const float* __restrict__ x, const float* __restrict__ y,
    const float* __restrict__ ctx, const float* __restrict__ xcg,
    const float* __restrict__ wih0, const float* __restrict__ whh0,
    const float* __restrict__ bih0, const float* __restrict__ bhh0,
    const float* __restrict__ wih1, const float* __restrict__ whh1,
    const float* __restrict__ bih1, const float* __restrict__ bhh1,
    const float* __restrict__ h0fi, const float* __restrict__ h1fi,
    const float* __restrict__ c0fi, const float* __restrict__ c1fi,
    ST* __restrict__ h1n, double* __restrict__ s2)
{
  __shared__ float ctxs[ROWS][CTXD+1];
  __shared__ float xcs[ROWS][CVD+1];
  __shared__ float h0s[2][ROWS][HH+1];
  __shared__ float h1s[2][ROWS][HH+1];
  const int r = threadIdx.x;
  const int b = blockIdx.x*ROWS + r;
  const int tid = threadIdx.y*ROWS + r;
  for (int i=tid; i<ROWS*CTXD; i+=ROWS*GRP){
    int rr = i/CTXD, ff = i - rr*CTXD;
    ctxs[rr][ff] = ctx[((size_t)blockIdx.x*ROWS + rr)*CTXD + ff];
  }
  for (int i=tid; i<ROWS*CVD; i+=ROWS*GRP){
    int rr = i/CVD, ff = i - rr*CVD;
    xcs[rr][ff] = xcg[((size_t)blockIdx.x*ROWS + rr)*CVD + ff];
  }
  const int ub = __builtin_amdgcn_readfirstlane(2*(int)threadIdx.y);
  const int wy = (int)threadIdx.y;
  float c0[2], c1[2];
  float bs0[2][4], bs1[2][4], w80[2][4], w81[2][4];
  #pragma unroll
  for (int jj=0;jj<2;++jj){
    const int j = ub+jj;
    const int jc = j<HH ? j : HH-1;
    c0[jj] = c0fi[(size_t)b*HH + jc];
    c1[jj] = c1fi[(size_t)b*HH + jc];
    #pragma unroll
    for (int g=0;g<4;++g){
      const int row = g*HH+jc;
      bs0[jj][g] = bih0[row] + bhh0[row];
      bs1[jj][g] = bih1[row] + bhh1[row];
      w80[jj][g] = wih0[(size_t)row*IN2 + 80];
      w81[jj][g] = wih0[(size_t)row*IN2 + 81];
    }
    if (j<HH){
      h0s[0][r][j] = h0fi[(size_t)b*HH + j];
      h1s[0][r][j] = h1fi[(size_t)b*HH + j];
    }
  }
  float tcur = x[(size_t)b*(TT*IND) + (TT-1)*IND + 7];
  float yi   = x[(size_t)b*(TT*IND) + (TT-1)*IND + 0];
  __syncthreads();
  int cur = 0;
  for (int s=0; s<NOUT; ++s){
    const int nxt = cur^1;
    tcur = fmodf(tcur + 15.f, 1440.f);
    float acc[2][4];
    #pragma unroll
    for (int jj=0;jj<2;++jj)
      #pragma unroll
      for (int g=0;g<4;++g)
        acc[jj][g] = bs0[jj][g] + tcur*w80[jj][g] + yi*w81[jj][g];
    #pragma unroll 8
    for (int k=0;k<CTXD;++k){
      const float v = ctxs[r][k];
      #pragma unroll
      for (int jj=0;jj<2;++jj){
        const int jc = (ub+jj)<HH ? (ub+jj) : HH-1;
        #pragma unroll
        for (int g=0;g<4;++g)
          acc[jj][g] += v * wih0[(size_t)(g*HH+jc)*IN2 + k];
      }
    }
    #pragma unroll 10
    for (int k=0;k<HH;++k){
      const float v = h0s[cur][r][k];
      #pragma unroll
      for (int jj=0;jj<2;++jj){
        const int jc = (ub+jj)<HH ? (ub+jj) : HH-1;
        #pragma unroll
        for (int g=0;g<4;++g)
          acc[jj][g] += v * whh0[(size_t)(g*HH+jc)*HH + k];
      }
    }
    #pragma unroll
    for (int jj=0;jj<2;++jj){
      const int j = ub+jj;
      float iv=sg(acc[jj][0]), fv=sg(acc[jj][1]), gv=th(acc[jj][2]), ov=sg(acc[jj][3]);
      float cn = fv*c0[jj] + iv*gv;
      c0[jj] = cn;
      if (j<HH) h0s[nxt][r][j] = ov*th(cn);
    }
    __syncthreads();
    #pragma unroll
    for (int jj=0;jj<2;++jj)
      #pragma unroll
      for (int g=0;g<4;++g) acc[jj][g] = bs1[jj][g];
    #pragma unroll 10
    for (int k=0;k<HH;++k){
      const float v = h0s[nxt][r][k];
      #pragma unroll
      for (int jj=0;jj<2;++jj){
        const int jc = (ub+jj)<HH ? (ub+jj) : HH-1;
        #pragma unroll
        for (int g=0;g<4;++g)
          acc[jj][g] += v * wih1[(size_t)(g*HH+jc)*HH + k];
      }
    }
    #pragma unroll 10
    for (int k=0;k<HH;++k){
      const float v = h1s[cur][r][k];
      #pragma unroll
      for (int jj=0;jj<2;++jj){
        const int jc = (ub+jj)<HH ? (ub+jj) : HH-1;
        #pragma unroll
        for (int g=0;g<4;++g)
          acc[jj][g] += v * whh1[(size_t)(g*HH+jc)*HH + k];
      }
    }
    #pragma unroll
    for (int jj=0;jj<2;++jj){
      const int j = ub+jj;
      float iv=sg(acc[jj][0]), fv=sg(acc[jj][1]), gv=th(acc[jj][2]), ov=sg(acc[jj][3]);
      float cn = fv*c1[jj] + iv*gv;
      c1[jj] = cn;
      if (j<HH) h1s[nxt][r][j] = ov*th(cn);
    }
    __syncthreads();
    // per-step feature stats: 4 features per wave, 16 waves cover 52+
    #pragma unroll 1
    for (int q=0;q<4;++q){
      const int f = wy*4 + q;
      if (f >= F2) break;
      float v;
      if (f < HH) v = h1s[nxt][r][f];
      else if (f < HH+CVD) v = xcs[r][f-HH];
      else if (f == HH+CVD) v = tcur;
      else v = yi;
      double sv = (double)v, sq = (double)v*(double)v;
      #pragma unroll
      for (int m=32;m>0;m>>=1){ sv += shfl_xor_d(sv,m); sq += shfl_xor_d(sq,m); }
      if (r==0){
        atomicAdd(&s2[((size_t)s*F2+f)*2+0], sv);
        atomicAdd(&s2[((size_t)s*F2+f)*2+1], sq);
      }
    }
    #pragma unroll
    for (int jj=0;jj<2;++jj){
      const int j = ub+jj;
      if (j<HH) stv(&h1n[((size_t)s*HH+j)*NB + b], h1s[nxt][r][j]);
    }
    yi = y[(size_t)b*NOUT + s];   // teacher forcing for next step
    cur = nxt;
  }
}

__global__ __launch_bounds__(256) void k_fin2(const double* __restrict__ s2, float* __restrict__ m2, float* __restrict__ r2){
  int i = blockIdx.x*256 + threadIdx.x;
  if (i >= NOUT*F2) return;
  double m = s2[i*2]/(double)NB;
  double var = s2[i*2+1]/(double)NB - m*m;
  if (var < 0.0) var = 0.0;
  m2[i] = (float)m;
  r2[i] = (float)(1.0/sqrt(var + 1e-5));
}

// ---------------- decoder pass 2: BN2 + dense readout ----------------
template<typename ST>
__global__ __launch_bounds__(256) void k_readout(
    const float* __restrict__ x, const float* __restrict__ y, const ST* __restrict__ h1n,
    const float* __restrict__ xcg, const float* __restrict__ m2, const float* __restrict__ r2,
    const float* __restrict__ g2, const float* __restrict__ b2,
    const float* __restrict__ Wd, const float* __restrict__ Bd,
    const float* __restrict__ Ud, const float* __restrict__ Cd, float* __restrict__ out)
{
  const int s  = blockIdx.y;
  const int rr = blockIdx.x*256 + threadIdx.x;
  float feat[F2];
  #pragma unroll
  for (int f=0; f<HH; ++f) feat[f] = ldv(&h1n[((size_t)s*HH+f)*NB + rr]);
  #pragma unroll
  for (int f=0; f<CVD; ++f) feat[HH+f] = xcg[(size_t)rr*CVD + f];
  float t0 = x[(size_t)rr*(TT*IND) + (TT-1)*IND + 7];
  for (int i=0;i<=s;++i) t0 = fmodf(t0 + 15.f, 1440.f);
  feat[HH+CVD] = t0;
  feat[HH+CVD+1] = (s==0) ? x[(size_t)rr*(TT*IND) + (TT-1)*IND + 0] : y[(size_t)rr*NOUT + (s-1)];
  #pragma unroll
  for (int f=0; f<F2; ++f)
    feat[f] = (feat[f] - m2[s*F2+f]) * r2[s*F2+f] * g2[f] + b2[f];
  float yv = Cd[s];
  #pragma unroll 1
  for (int jb=0; jb<HID; jb+=10){
    float a[10];
    #pragma unroll
    for (int jt=0;jt<10;++jt) a[jt] = Bd[(size_t)s*HID + jb + jt];
    #pragma unroll 4
    for (int k=0;k<F2;++k){
      const float v = feat[k];
      #pragma unroll
      for (int jt=0;jt<10;++jt)
        a[jt] += v * Wd[((size_t)s*F2 + k)*HID + jb + jt];
    }
    #pragma unroll
    for (int jt=0;jt<10;++jt)
      yv += fmaxf(a[jt], 0.f) * Ud[(size_t)s*HID + jb + jt];
  }
  out[(size_t)rr*NOUT + s] = yv;
}

// ---------------- host ----------------
extern "C" void kernel_launch(void* const* d_in, const int* in_sizes, int n_in,
                              void* d_out, int out_size, void* d_ws, size_t ws_size,
                              hipStream_t stream)
{
  const float* x    = (const float*)d_in[0];
  const float* y    = (const float*)d_in[1];
  const float* h0i  = (const float*)d_in[2];
  const float* c0i  = (const float*)d_in[3];
  const float* wih0 = (const float*)d_in[4];
  const float* whh0 = (const float*)d_in[5];
  const float* bih0 = (const float*)d_in[6];
  const float* bhh0 = (const float*)d_in[7];
  const float* wih1 = (const float*)d_in[8];
  const float* whh1 = (const float*)d_in[9];
  const float* bih1 = (const float*)d_in[10];
  const float* bhh1 = (const float*)d_in[11];
  const float* w2ih0= (const float*)d_in[12];
  const float* w2hh0= (const float*)d_in[13];
  const float* b2ih0= (const float*)d_in[14];
  const float* b2hh0= (const float*)d_in[15];
  const float* w2ih1= (const float*)d_in[16];
  const float* w2hh1= (const float*)d_in[17];
  const float* b2ih1= (const float*)d_in[18];
  const float* b2hh1= (const float*)d_in[19];
  const float* c1w  = (const float*)d_in[20];
  const float* c1b  = (const float*)d_in[21];
  const float* c2w  = (const float*)d_in[22];
  const float* c2b  = (const float*)d_in[23];
  const float* c3w  = (const float*)d_in[24];
  const float* c3b  = (const float*)d_in[25];
  const float* fcw  = (const float*)d_in[26];
  const float* fcb  = (const float*)d_in[27];
  const float* bn1g = (const float*)d_in[28];
  const float* bn1b = (const float*)d_in[29];
  const float* bn2g = (const float*)d_in[30];
  const float* bn2b = (const float*)d_in[31];
  const float* Wd   = (const float*)d_in[32];
  const float* Bd   = (const float*)d_in[33];
  const float* Ud   = (const float*)d_in[34];
  const float* Cd   = (const float*)d_in[35];
  float* out = (float*)d_out;

  char* base = (char*)d_ws;
  size_t off = 0;
  auto take = [&](size_t bytes)->char*{
    char* p = base + off;
    off = (off + bytes + 255) & ~(size_t)255;
    return p;
  };
  float*  h0f = (float*) take((size_t)NB*HH*sizeof(float));
  float*  h1f = (float*) take((size_t)NB*HH*sizeof(float));
  float*  c0f = (float*) take((size_t)NB*HH*sizeof(float));
  float*  c1f = (float*) take((size_t)NB*HH*sizeof(float));
  float*  xcg = (float*) take((size_t)NB*CVD*sizeof(float));
  float*  ctx = (float*) take((size_t)NB*CTXD*sizeof(float));
  double* s1  = (double*)take((size_t)CTXD*2*sizeof(double));
  float*  st1 = (float*) take((size_t)CTXD*2*sizeof(float));
  double* s2  = (double*)take((size_t)NOUT*F2*2*sizeof(double));
  float*  m2  = (float*) take((size_t)NOUT*F2*sizeof(float));
  float*  r2  = (float*) take((size_t)NOUT*F2*sizeof(float));
  size_t fixed = off;
  size_t rem = (ws_size > fixed) ? (ws_size - fixed) : 0;
  bool f32st = rem >= (size_t)NOUT*HH*NB*sizeof(float);
  void* h1n = (void*)(base + off);

  k_zero<<<dim3((NOUT*F2*2 + 255)/256), dim3(256), 0, stream>>>(s1, s2);
  k_encoder<<<dim3(NB/ROWS), dim3(ROWS,GRP), 0, stream>>>(x, h0i, c0i,
      wih0, whh0, bih0, bhh0, wih1, whh1, bih1, bhh1, h0f, h1f, c0f, c1f);
  k_conv<<<dim3(NB), dim3(64), 0, stream>>>(x, c1w, c1b, c2w, c2b, c3w, c3b, fcw, fcb, xcg);
  k_bn1s<<<dim3(NB/128), dim3(128), 0, stream>>>(h0f, h1f, xcg, s1);
  k_fin1<<<dim3(1), dim3(128), 0, stream>>>(s1, st1);
  k_context<<<dim3((NB*CTXD + 255)/256), dim3(256), 0, stream>>>(h0f, h1f, xcg, st1, bn1g, bn1b, ctx);
  if (f32st){
    k_dec1<float><<<dim3(NB/ROWS), dim3(ROWS,GRP), 0, stream>>>(x, y, ctx, xcg,
        w2ih0, w2hh0, b2ih0, b2hh0, w2ih1, w2hh1, b2ih1, b2hh1,
        h0f, h1f, c0f, c1f, (float*)h1n, s2);
    k_fin2<<<dim3((NOUT*F2 + 255)/256), dim3(256), 0, stream>>>(s2, m2, r2);
    k_readout<float><<<dim3(NB/256, NOUT), dim3(256), 0, stream>>>(x, y, (const float*)h1n,
        xcg, m2, r2, bn2g, bn2b, Wd, Bd, Ud, Cd, out);
  } else {
    k_dec1<__hip_bfloat16><<<dim3(NB/ROWS), dim3(ROWS,GRP), 0, stream>>>(x, y, ctx, xcg,
        w2ih0, w2hh0, b2ih0, b2hh0, w2ih1, w2hh1, b2ih1, b2hh1,
        h0f, h1f, c0f, c1f, (__hip_bfloat16*)h1n, s2);
    k_fin2<<<dim3((NOUT*F2 + 255)/256), dim3(256), 0, stream>>>(s2, m2, r2);
    k_readout<__hip_bfloat16><<<dim3(NB/256, NOUT), dim3(256), 0, stream>>>(x, y, (const __hip_bfloat16*)h1n,
        xcg, m2, r2, bn2g, bn2b, Wd, Bd, Ud, Cd, out);
  }
}